// Round 5
// baseline (293.706 us; speedup 1.0000x reference)
//
#include <hip/hip_runtime.h>
#include <hip/hip_bf16.h>

#define C_DIM 384
#define H_NUM 6
#define HS    64
#define B_DIM 128
#define T_DIM 256
#define NROWS (B_DIM * T_DIM)  // 32768

typedef unsigned short u16;
typedef unsigned int u32;
typedef short bf16x8 __attribute__((ext_vector_type(8)));
typedef float floatx4 __attribute__((ext_vector_type(4)));

__device__ __forceinline__ u16 f2b(float f) {
  __hip_bfloat16 h = __float2bfloat16(f);
  u16 u;
  __builtin_memcpy(&u, &h, 2);
  return u;
}
// async global->LDS, 16B per lane. LDS dest is wave-uniform base + lane*16.
__device__ __forceinline__ void gload_lds16(const void* g, void* lds) {
  __builtin_amdgcn_global_load_lds(
      (const __attribute__((address_space(1))) u32*)g,
      (__attribute__((address_space(3))) u32*)lds, 16, 0, 0);
}

// ---------------------------------------------------------------------------
// Prep (r4-verified, unchanged): x fp32 -> bf16 xb (K-permuted per row) AND
// weights -> bf16 (K-permuted). Rule-21: linear DMA dest + inverse-permuted
// source + XOR'd fragment read in the consumer.
// ---------------------------------------------------------------------------
__global__ __launch_bounds__(256) void prep_kernel(
    const float* __restrict__ x, const float* __restrict__ Wq,
    const float* __restrict__ Wk, const float* __restrict__ Wv,
    const float* __restrict__ Wp, u16* __restrict__ xb,
    u16* __restrict__ Wh, u16* __restrict__ Wpt) {
  const int bid = blockIdx.x;
  const int tid = threadIdx.x;
  if (bid < 6144) {  // x: 12,582,912 elems = 6144*256 threads x 8
    const int i = bid * 256 + tid;
    const int row = (i * 8) / C_DIM;
    const int c8 = (i * 8) % C_DIM;
    const int cs = c8 ^ ((row & 7) << 3);  // XOR bits 3-5, within 64-block
    const float* p = x + (size_t)row * C_DIM + cs;
    const float4 f0 = *(const float4*)p;
    const float4 f1 = *(const float4*)(p + 4);
    bf16x8 pk;
    pk[0] = (short)f2b(f0.x); pk[1] = (short)f2b(f0.y);
    pk[2] = (short)f2b(f0.z); pk[3] = (short)f2b(f0.w);
    pk[4] = (short)f2b(f1.x); pk[5] = (short)f2b(f1.y);
    pk[6] = (short)f2b(f1.z); pk[7] = (short)f2b(f1.w);
    ((bf16x8*)xb)[i] = pk;
  } else {  // weights: 442368 + 147456 = 589824 = 2304*256
    const int idx = (bid - 6144) * 256 + tid;
    const int WHN = H_NUM * 192 * C_DIM;  // 442368
    if (idx < WHN) {
      int h = idx / (192 * C_DIM);
      int rem = idx % (192 * C_DIM);
      int r = rem / C_DIM, c = rem % C_DIM;
      int tz = r >> 6, d = r & 63;
      const int cs = c ^ ((r & 7) << 3);
      const float* W = (tz == 0) ? Wq : (tz == 1) ? Wk : Wv;
      Wh[idx] = f2b(W[((size_t)h * C_DIM + cs) * HS + d]);
    } else {
      int j = idx - WHN;
      int n = j / C_DIM, c = j % C_DIM;
      const int cs = c ^ ((n & 7) << 3);
      Wpt[j] = f2b(Wp[cs * C_DIM + n]);
    }
  }
}

// ---------------------------------------------------------------------------
// FUSED kernel: per-(b,h) block. 512 threads = 8 waves. NOW 2 blocks/CU:
// LDS cut 116736 -> 75776 B so two blocks co-reside and their serial phases
// (GEMM staging waits / scatter / attn) overlap across blocks (m114).
// Phase 1: GEMM 256x192x384, single-buffered BK=64 DMA staging (r2-verified
//          loop), XOR-swizzled conflict-free fragment reads (r4-verified).
// Phase 2: scatter q+k to LDS -> barrier -> preload q-fragments to VGPR ->
//          barrier -> scatter v OVER the q region (q transient staging).
// Phase 3: causal flash attention from LDS; P halved to [16][40] per wave.
// LDS map (u16 offsets), total 37888 u16 = 75776 B:
//   GEMM: As[256][64] @0 (16384), Bs[192][64] @16384 (ends 28672)
//   attn: KLS[32*512] @0 (16384), VQS[64][256] @16384 (q then v; 16384),
//         PLS 8 x [16][40] @32768 (5120, ends 37888)
// ---------------------------------------------------------------------------
#define AS_OFF  0
#define BS_OFF  16384
#define KLS_OFF 0
#define VQS_OFF 16384
#define PLS_OFF 32768

template <bool DIAG>
__device__ __forceinline__ void attn_chunk_f(int c, int mt, int lane, int ln,
                                             int qd, const bf16x8* qf,
                                             const u16* smem, u16* Pw,
                                             floatx4* oacc, float* lsum) {
#pragma unroll
  for (int hf = 0; hf < 2; ++hf) {  // kc2-half: st pair {2hf, 2hf+1}
    floatx4 sacc[2];
#pragma unroll
    for (int s2 = 0; s2 < 2; ++s2) {
      const int st = hf * 2 + s2;
      sacc[s2] = floatx4{0.f, 0.f, 0.f, 0.f};
#pragma unroll
      for (int kc = 0; kc < 2; ++kc) {
        bf16x8 kf = *(const bf16x8*)&smem[KLS_OFF +
                                          ((c * 4 + st) * 2 + kc) * 512 +
                                          lane * 8];
        sacc[s2] = __builtin_amdgcn_mfma_f32_16x16x32_bf16(qf[kc], kf,
                                                           sacc[s2], 0, 0, 0);
      }
    }
#pragma unroll
    for (int s2 = 0; s2 < 2; ++s2) {
      const int st = hf * 2 + s2;
#pragma unroll
      for (int r = 0; r < 4; ++r) {
        float p = __expf(sacc[s2][r] * 0.125f);
        if (DIAG) {
          const bool ok = (c * 64 + st * 16 + ln) <= (mt * 16 + qd * 4 + r);
          p = ok ? p : 0.f;
        }
        lsum[r] += p;
        Pw[(qd * 4 + r) * 40 + s2 * 16 + ln] = f2b(p);
      }
    }
    // wave-local P round-trip (in-order LDS per wave; verified pattern)
    bf16x8 pf = *(const bf16x8*)&Pw[ln * 40 + qd * 8];
#pragma unroll
    for (int dt = 0; dt < 4; ++dt) {
      bf16x8 vf = *(const bf16x8*)&smem[VQS_OFF + (dt * 16 + ln) * 256 +
                                        ((c * 64 + hf * 32 + qd * 8) ^
                                         ((ln & 7) << 3))];
      oacc[dt] =
          __builtin_amdgcn_mfma_f32_16x16x32_bf16(pf, vf, oacc[dt], 0, 0, 0);
    }
  }
}

__global__ __launch_bounds__(512, 4) void qkv_attn_fused(
    const u16* __restrict__ xb, const u16* __restrict__ Wh,
    u16* __restrict__ y) {
  __shared__ __align__(16) u16 smem[37888];  // 75776 B -> 2 blocks/CU
  const int b = blockIdx.x;
  const int h = blockIdx.y;
  const u16* a_rows = xb + (size_t)b * 256 * C_DIM;
  const u16* wbase = Wh + (size_t)h * 192 * C_DIM;

  const int tid = threadIdx.x;
  const int lane = tid & 63;
  const int w = tid >> 6;          // 0..7
  const int lr = lane >> 3;        // DMA staging row within 8-row strip
  const int lkc = (lane & 7) * 8;  // DMA staging col (u16)
  const int qd = lane >> 4;
  const int ln = lane & 15;
  const int sx = (ln & 7) << 3;    // fragment-read XOR key
  const int wm = (w >> 1) * 64;    // GEMM row group (0,64,128,192)
  const int wn = (w & 1) * 96;     // GEMM col group (0,96)

  // ---------------- Phase 1: GEMM (single-buf, r2-verified loop) ----------
  floatx4 acc[4][6];
#pragma unroll
  for (int i = 0; i < 4; ++i)
#pragma unroll
    for (int j = 0; j < 6; ++j) acc[i][j] = floatx4{0.f, 0.f, 0.f, 0.f};

  for (int kb = 0; kb < 6; ++kb) {
    const int k0 = kb * 64;
    __syncthreads();  // prior fragment reads done; LDS writable
    // A: 32 strips of 8 rows / 8 waves = 4 per wave
#pragma unroll
    for (int s = 0; s < 4; ++s) {
      const int rbase = (s * 8 + w) * 8;
      gload_lds16(a_rows + (size_t)(rbase + lr) * C_DIM + k0 + lkc,
                  smem + AS_OFF + rbase * 64);
    }
    // B: 24 strips of 8 rows / 8 waves = 3 per wave
#pragma unroll
    for (int s = 0; s < 3; ++s) {
      const int rbase = (s * 8 + w) * 8;
      gload_lds16(wbase + (size_t)(rbase + lr) * C_DIM + k0 + lkc,
                  smem + BS_OFF + rbase * 64);
    }
    __syncthreads();  // drains DMA (vmcnt) before reads

#pragma unroll
    for (int kk = 0; kk < 2; ++kk) {
      bf16x8 af[4], bf[6];
#pragma unroll
      for (int mt = 0; mt < 4; ++mt)
        af[mt] = *(const bf16x8*)&smem[AS_OFF + (wm + mt * 16 + ln) * 64 +
                                       ((kk * 32 + qd * 8) ^ sx)];
#pragma unroll
      for (int nt = 0; nt < 6; ++nt)
        bf[nt] = *(const bf16x8*)&smem[BS_OFF + (wn + nt * 16 + ln) * 64 +
                                       ((kk * 32 + qd * 8) ^ sx)];
#pragma unroll
      for (int mt = 0; mt < 4; ++mt)
#pragma unroll
        for (int nt = 0; nt < 6; ++nt)
          acc[mt][nt] = __builtin_amdgcn_mfma_f32_16x16x32_bf16(
              af[mt], bf[nt], acc[mt][nt], 0, 0, 0);
    }
  }
  __syncthreads();  // all fragment reads consumed; LDS fully dead

  // ---------------- Phase 2a: scatter q (into VQS) and k (into KLS) -------
  // C/D layout: col = c0 + ln, row t = wm + mt*16 + qd*4 + r.
#pragma unroll
  for (int nt = 0; nt < 6; ++nt) {
    const int c0 = wn + nt * 16;  // wave-uniform
    if (c0 < 128) {
#pragma unroll
      for (int mt = 0; mt < 4; ++mt) {
#pragma unroll
        for (int r = 0; r < 4; ++r) {
          const int t = wm + mt * 16 + qd * 4 + r;
          const u16 val = f2b(acc[mt][nt][r]);
          if (c0 < 64) {  // q -> VQS [t][64], XOR-swizzled col
            smem[VQS_OFF + t * 64 + ((c0 + ln) ^ ((t & 7) << 3))] = val;
          } else {  // k -> fragment-major KLS
            const int d = c0 - 64 + ln;
            smem[KLS_OFF + ((t >> 4) << 10) + ((d >> 5) << 9) +
                 (((d >> 3) & 3) << 7) + ((t & 15) << 3) + (d & 7)] = val;
          }
        }
      }
    }
  }
  __syncthreads();

  // ---------------- Phase 2b: preload q-fragments for both mt's -----------
  bf16x8 qf2[2][2];
#pragma unroll
  for (int i = 0; i < 2; ++i) {
    const int mt = i ? (15 - w) : w;
#pragma unroll
    for (int kc = 0; kc < 2; ++kc)
      qf2[i][kc] = *(const bf16x8*)&smem[VQS_OFF + (mt * 16 + ln) * 64 +
                                         ((kc * 32 + qd * 8) ^ sx)];
  }
  __syncthreads();  // all q reads done; VQS writable

  // ---------------- Phase 2c: scatter v over VQS ([d][t], XOR-swizzled) ---
#pragma unroll
  for (int nt = 2; nt < 6; ++nt) {
    const int c0 = wn + nt * 16;
    if (c0 >= 128) {
#pragma unroll
      for (int mt = 0; mt < 4; ++mt) {
#pragma unroll
        for (int r = 0; r < 4; ++r) {
          const int t = wm + mt * 16 + qd * 4 + r;
          const int dv = c0 - 128 + ln;
          smem[VQS_OFF + dv * 256 + (t ^ ((dv & 7) << 3))] =
              f2b(acc[mt][nt][r]);
        }
      }
    }
  }
  __syncthreads();

  // ---------------- Phase 3: causal flash attention ----------------
  u16* Pw = smem + PLS_OFF + w * 640;
#pragma unroll
  for (int i = 0; i < 2; ++i) {
    const int mt = i ? (15 - w) : w;

    floatx4 oacc[4];
    float lsum[4];
#pragma unroll
    for (int dt = 0; dt < 4; ++dt) oacc[dt] = floatx4{0.f, 0.f, 0.f, 0.f};
#pragma unroll
    for (int r = 0; r < 4; ++r) lsum[r] = 0.f;

    const int cmax = mt >> 2;
    for (int c = 0; c < cmax; ++c)
      attn_chunk_f<false>(c, mt, lane, ln, qd, qf2[i], smem, Pw, oacc, lsum);
    attn_chunk_f<true>(cmax, mt, lane, ln, qd, qf2[i], smem, Pw, oacc, lsum);

#pragma unroll
    for (int off = 1; off < 16; off <<= 1)
#pragma unroll
      for (int r = 0; r < 4; ++r) lsum[r] += __shfl_xor(lsum[r], off);

    // y written with per-row col permutation for proj's swizzled read
#pragma unroll
    for (int r = 0; r < 4; ++r) {
      const float inv = 1.f / lsum[r];
      const int t = mt * 16 + qd * 4 + r;
      const int sy = (t & 7) << 3;
      u16* yo = y + ((size_t)b * T_DIM + t) * C_DIM + h * HS;
#pragma unroll
      for (int dt = 0; dt < 4; ++dt)
        yo[(dt * 16 + ln) ^ sy] = f2b(oacc[dt][r] * inv);
    }
  }
}

// ---------------------------------------------------------------------------
// Kernel C: output projection (r4-verified, unchanged).
// ---------------------------------------------------------------------------
__global__ __launch_bounds__(256) void proj_gemm(
    const u16* __restrict__ yb, const u16* __restrict__ Wpt,
    const float* __restrict__ bp, float* __restrict__ out) {
  __shared__ u16 As[128 * 64];
  __shared__ u16 Bs[128 * 64];
  const int row0 = blockIdx.x * 128;
  const int n0 = blockIdx.y * 128;
  const u16* a_rows = yb + (size_t)row0 * C_DIM;
  const u16* bt_rows = Wpt + (size_t)n0 * C_DIM;

  const int tid = threadIdx.x;
  const int lane = tid & 63;
  const int w = tid >> 6;
  const int lr = lane >> 3;
  const int lkc = (lane & 7) * 8;
  const int qd = lane >> 4;
  const int ln = lane & 15;
  const int sx = (ln & 7) << 3;
  const int mw = (w >> 1) * 64;
  const int nw = (w & 1) * 64;

  floatx4 acc[4][4];
#pragma unroll
  for (int i = 0; i < 4; ++i)
#pragma unroll
    for (int j = 0; j < 4; ++j) acc[i][j] = floatx4{0.f, 0.f, 0.f, 0.f};

  for (int kb = 0; kb < C_DIM / 64; ++kb) {
    const int k0 = kb * 64;
    __syncthreads();
#pragma unroll
    for (int s = 0; s < 4; ++s) {
      const int rbase = (s * 4 + w) * 8;
      gload_lds16(a_rows + (size_t)(rbase + lr) * C_DIM + k0 + lkc,
                  As + rbase * 64);
      gload_lds16(bt_rows + (size_t)(rbase + lr) * C_DIM + k0 + lkc,
                  Bs + rbase * 64);
    }
    __syncthreads();

#pragma unroll
    for (int kk = 0; kk < 2; ++kk) {
      bf16x8 af[4], bf[4];
#pragma unroll
      for (int mt = 0; mt < 4; ++mt)
        af[mt] = *(const bf16x8*)&As[(mw + mt * 16 + ln) * 64 +
                                     ((kk * 32 + qd * 8) ^ sx)];
#pragma unroll
      for (int nt = 0; nt < 4; ++nt)
        bf[nt] = *(const bf16x8*)&Bs[(nw + nt * 16 + ln) * 64 +
                                     ((kk * 32 + qd * 8) ^ sx)];
#pragma unroll
      for (int mt = 0; mt < 4; ++mt)
#pragma unroll
        for (int nt = 0; nt < 4; ++nt)
          acc[mt][nt] = __builtin_amdgcn_mfma_f32_16x16x32_bf16(
              af[mt], bf[nt], acc[mt][nt], 0, 0, 0);
    }
  }

#pragma unroll
  for (int nt = 0; nt < 4; ++nt) {
    const int col = n0 + nw + nt * 16 + ln;
    const float bias = bp[col];
#pragma unroll
    for (int mt = 0; mt < 4; ++mt) {
#pragma unroll
      for (int r = 0; r < 4; ++r) {
        const int grow = row0 + mw + mt * 16 + qd * 4 + r;
        out[(size_t)grow * C_DIM + col] = acc[mt][nt][r] + bias;
      }
    }
  }
}

// ---------------------------------------------------------------------------
extern "C" void kernel_launch(void* const* d_in, const int* in_sizes, int n_in,
                              void* d_out, int out_size, void* d_ws, size_t ws_size,
                              hipStream_t stream) {
  const float* x  = (const float*)d_in[0];
  const float* Wq = (const float*)d_in[1];
  const float* Wk = (const float*)d_in[2];
  const float* Wv = (const float*)d_in[3];
  const float* Wp = (const float*)d_in[4];
  const float* bp = (const float*)d_in[5];
  float* out = (float*)d_out;

  const size_t n_x = (size_t)NROWS * C_DIM;  // 12,582,912

  u16* Wh  = (u16*)d_ws;                       // [6][192][384] (K-permuted)
  u16* Wpt = Wh + (size_t)H_NUM * 192 * C_DIM; // [384][384]   (K-permuted)
  u16* xb  = Wpt + C_DIM * C_DIM;              // [32768][384] (K-permuted)
  u16* y   = xb + n_x;                         // [32768][384] (col-permuted)
  // ws: ~0.9 + 0.3 + 24 + 24 = ~49 MB

  prep_kernel<<<6144 + 2304, 256, 0, stream>>>(x, Wq, Wk, Wv, Wp, xb, Wh, Wpt);
  qkv_attn_fused<<<dim3(B_DIM, H_NUM), 512, 0, stream>>>(xb, Wh, y);
  proj_gemm<<<dim3(NROWS / 128, 3), 256, 0, stream>>>(y, Wpt, bp, out);
}

// Round 6
// 186.844 us; speedup vs baseline: 1.5719x; 1.5719x over previous
//
#include <hip/hip_runtime.h>
#include <hip/hip_bf16.h>

#define C_DIM 384
#define H_NUM 6
#define HS    64
#define B_DIM 128
#define T_DIM 256
#define NROWS (B_DIM * T_DIM)  // 32768

typedef unsigned short u16;
typedef unsigned int u32;
typedef short bf16x8 __attribute__((ext_vector_type(8)));
typedef float floatx4 __attribute__((ext_vector_type(4)));

__device__ __forceinline__ u16 f2b(float f) {
  __hip_bfloat16 h = __float2bfloat16(f);
  u16 u;
  __builtin_memcpy(&u, &h, 2);
  return u;
}
// async global->LDS, 16B per lane. LDS dest is wave-uniform base + lane*16.
__device__ __forceinline__ void gload_lds16(const void* g, void* lds) {
  __builtin_amdgcn_global_load_lds(
      (const __attribute__((address_space(1))) u32*)g,
      (__attribute__((address_space(3))) u32*)lds, 16, 0, 0);
}

// ---------------------------------------------------------------------------
// Prep (r4-verified, unchanged): x fp32 -> bf16 xb (K-permuted per row) AND
// weights -> bf16 (K-permuted). Rule-21: linear DMA dest + inverse-permuted
// source + XOR'd fragment read in the consumer.
// ---------------------------------------------------------------------------
__global__ __launch_bounds__(256) void prep_kernel(
    const float* __restrict__ x, const float* __restrict__ Wq,
    const float* __restrict__ Wk, const float* __restrict__ Wv,
    const float* __restrict__ Wp, u16* __restrict__ xb,
    u16* __restrict__ Wh, u16* __restrict__ Wpt) {
  const int bid = blockIdx.x;
  const int tid = threadIdx.x;
  if (bid < 6144) {  // x: 12,582,912 elems = 6144*256 threads x 8
    const int i = bid * 256 + tid;
    const int row = (i * 8) / C_DIM;
    const int c8 = (i * 8) % C_DIM;
    const int cs = c8 ^ ((row & 7) << 3);  // XOR bits 3-5, within 64-block
    const float* p = x + (size_t)row * C_DIM + cs;
    const float4 f0 = *(const float4*)p;
    const float4 f1 = *(const float4*)(p + 4);
    bf16x8 pk;
    pk[0] = (short)f2b(f0.x); pk[1] = (short)f2b(f0.y);
    pk[2] = (short)f2b(f0.z); pk[3] = (short)f2b(f0.w);
    pk[4] = (short)f2b(f1.x); pk[5] = (short)f2b(f1.y);
    pk[6] = (short)f2b(f1.z); pk[7] = (short)f2b(f1.w);
    ((bf16x8*)xb)[i] = pk;
  } else {  // weights: 442368 + 147456 = 589824 = 2304*256
    const int idx = (bid - 6144) * 256 + tid;
    const int WHN = H_NUM * 192 * C_DIM;  // 442368
    if (idx < WHN) {
      int h = idx / (192 * C_DIM);
      int rem = idx % (192 * C_DIM);
      int r = rem / C_DIM, c = rem % C_DIM;
      int tz = r >> 6, d = r & 63;
      const int cs = c ^ ((r & 7) << 3);
      const float* W = (tz == 0) ? Wq : (tz == 1) ? Wk : Wv;
      Wh[idx] = f2b(W[((size_t)h * C_DIM + cs) * HS + d]);
    } else {
      int j = idx - WHN;
      int n = j / C_DIM, c = j % C_DIM;
      const int cs = c ^ ((n & 7) << 3);
      Wpt[j] = f2b(Wp[cs * C_DIM + n]);
    }
  }
}

// ---------------------------------------------------------------------------
// FUSED kernel: per-(b,h) block. 512 threads = 8 waves. 2 blocks/CU target:
// LDS 75776 B (x2 = 151.5 KB <= 160 KB) and __launch_bounds__(512, 2)
// (empirically: 2nd arg behaves as min BLOCKS/CU on this toolchain; r5's
// (512,4) forced a 64-VGPR cap -> acc spill -> 423 MB scratch writes).
// (512,2) caps regs at 128; body needs ~112 -> no spill, 2 blocks resident.
// Phase 1: GEMM 256x192x384, single-buffered BK=64 DMA staging, XOR-swizzled
//          conflict-free fragment reads. Cross-block overlap hides staging.
// Phase 2: scatter q+k -> barrier -> preload q-frags to VGPR -> barrier ->
//          scatter v over the q region (transient staging).
// Phase 3: causal flash attention from LDS; per-wave P [16][40].
// LDS map (u16 offsets), total 37888 u16 = 75776 B:
//   GEMM: As[256][64] @0, Bs[192][64] @16384 (ends 28672)
//   attn: KLS[32*512] @0, VQS[64][256] @16384, PLS 8x[16][40] @32768
// ---------------------------------------------------------------------------
#define AS_OFF  0
#define BS_OFF  16384
#define KLS_OFF 0
#define VQS_OFF 16384
#define PLS_OFF 32768

template <bool DIAG>
__device__ __forceinline__ void attn_chunk_f(int c, int mt, int lane, int ln,
                                             int qd, const bf16x8* qf,
                                             const u16* smem, u16* Pw,
                                             floatx4* oacc, float* lsum) {
#pragma unroll
  for (int hf = 0; hf < 2; ++hf) {  // kc2-half: st pair {2hf, 2hf+1}
    floatx4 sacc[2];
#pragma unroll
    for (int s2 = 0; s2 < 2; ++s2) {
      const int st = hf * 2 + s2;
      sacc[s2] = floatx4{0.f, 0.f, 0.f, 0.f};
#pragma unroll
      for (int kc = 0; kc < 2; ++kc) {
        bf16x8 kf = *(const bf16x8*)&smem[KLS_OFF +
                                          ((c * 4 + st) * 2 + kc) * 512 +
                                          lane * 8];
        sacc[s2] = __builtin_amdgcn_mfma_f32_16x16x32_bf16(qf[kc], kf,
                                                           sacc[s2], 0, 0, 0);
      }
    }
#pragma unroll
    for (int s2 = 0; s2 < 2; ++s2) {
      const int st = hf * 2 + s2;
#pragma unroll
      for (int r = 0; r < 4; ++r) {
        float p = __expf(sacc[s2][r] * 0.125f);
        if (DIAG) {
          const bool ok = (c * 64 + st * 16 + ln) <= (mt * 16 + qd * 4 + r);
          p = ok ? p : 0.f;
        }
        lsum[r] += p;
        Pw[(qd * 4 + r) * 40 + s2 * 16 + ln] = f2b(p);
      }
    }
    // wave-local P round-trip (in-order LDS per wave; verified pattern)
    bf16x8 pf = *(const bf16x8*)&Pw[ln * 40 + qd * 8];
#pragma unroll
    for (int dt = 0; dt < 4; ++dt) {
      bf16x8 vf = *(const bf16x8*)&smem[VQS_OFF + (dt * 16 + ln) * 256 +
                                        ((c * 64 + hf * 32 + qd * 8) ^
                                         ((ln & 7) << 3))];
      oacc[dt] =
          __builtin_amdgcn_mfma_f32_16x16x32_bf16(pf, vf, oacc[dt], 0, 0, 0);
    }
  }
}

__global__ __launch_bounds__(512, 2) void qkv_attn_fused(
    const u16* __restrict__ xb, const u16* __restrict__ Wh,
    u16* __restrict__ y) {
  __shared__ __align__(16) u16 smem[37888];  // 75776 B -> 2 blocks/CU
  const int b = blockIdx.x;
  const int h = blockIdx.y;
  const u16* a_rows = xb + (size_t)b * 256 * C_DIM;
  const u16* wbase = Wh + (size_t)h * 192 * C_DIM;

  const int tid = threadIdx.x;
  const int lane = tid & 63;
  const int w = tid >> 6;          // 0..7
  const int lr = lane >> 3;        // DMA staging row within 8-row strip
  const int lkc = (lane & 7) * 8;  // DMA staging col (u16)
  const int qd = lane >> 4;
  const int ln = lane & 15;
  const int sx = (ln & 7) << 3;    // fragment-read XOR key
  const int wm = (w >> 1) * 64;    // GEMM row group (0,64,128,192)
  const int wn = (w & 1) * 96;     // GEMM col group (0,96)

  // ---------------- Phase 1: GEMM (single-buf) ----------
  floatx4 acc[4][6];
#pragma unroll
  for (int i = 0; i < 4; ++i)
#pragma unroll
    for (int j = 0; j < 6; ++j) acc[i][j] = floatx4{0.f, 0.f, 0.f, 0.f};

  for (int kb = 0; kb < 6; ++kb) {
    const int k0 = kb * 64;
    __syncthreads();  // prior fragment reads done; LDS writable
    // A: 32 strips of 8 rows / 8 waves = 4 per wave
#pragma unroll
    for (int s = 0; s < 4; ++s) {
      const int rbase = (s * 8 + w) * 8;
      gload_lds16(a_rows + (size_t)(rbase + lr) * C_DIM + k0 + lkc,
                  smem + AS_OFF + rbase * 64);
    }
    // B: 24 strips of 8 rows / 8 waves = 3 per wave
#pragma unroll
    for (int s = 0; s < 3; ++s) {
      const int rbase = (s * 8 + w) * 8;
      gload_lds16(wbase + (size_t)(rbase + lr) * C_DIM + k0 + lkc,
                  smem + BS_OFF + rbase * 64);
    }
    __syncthreads();  // drains DMA (vmcnt) before reads

#pragma unroll
    for (int kk = 0; kk < 2; ++kk) {
      bf16x8 af[4], bf[6];
#pragma unroll
      for (int mt = 0; mt < 4; ++mt)
        af[mt] = *(const bf16x8*)&smem[AS_OFF + (wm + mt * 16 + ln) * 64 +
                                       ((kk * 32 + qd * 8) ^ sx)];
#pragma unroll
      for (int nt = 0; nt < 6; ++nt)
        bf[nt] = *(const bf16x8*)&smem[BS_OFF + (wn + nt * 16 + ln) * 64 +
                                       ((kk * 32 + qd * 8) ^ sx)];
#pragma unroll
      for (int mt = 0; mt < 4; ++mt)
#pragma unroll
        for (int nt = 0; nt < 6; ++nt)
          acc[mt][nt] = __builtin_amdgcn_mfma_f32_16x16x32_bf16(
              af[mt], bf[nt], acc[mt][nt], 0, 0, 0);
    }
  }
  __syncthreads();  // all fragment reads consumed; LDS fully dead

  // ---------------- Phase 2a: scatter q (into VQS) and k (into KLS) -------
  // C/D layout: col = c0 + ln, row t = wm + mt*16 + qd*4 + r.
#pragma unroll
  for (int nt = 0; nt < 6; ++nt) {
    const int c0 = wn + nt * 16;  // wave-uniform
    if (c0 < 128) {
#pragma unroll
      for (int mt = 0; mt < 4; ++mt) {
#pragma unroll
        for (int r = 0; r < 4; ++r) {
          const int t = wm + mt * 16 + qd * 4 + r;
          const u16 val = f2b(acc[mt][nt][r]);
          if (c0 < 64) {  // q -> VQS [t][64], XOR-swizzled col
            smem[VQS_OFF + t * 64 + ((c0 + ln) ^ ((t & 7) << 3))] = val;
          } else {  // k -> fragment-major KLS
            const int d = c0 - 64 + ln;
            smem[KLS_OFF + ((t >> 4) << 10) + ((d >> 5) << 9) +
                 (((d >> 3) & 3) << 7) + ((t & 15) << 3) + (d & 7)] = val;
          }
        }
      }
    }
  }
  __syncthreads();

  // ---------------- Phase 2b: preload q-fragments for both mt's -----------
  bf16x8 qf2[2][2];
#pragma unroll
  for (int i = 0; i < 2; ++i) {
    const int mt = i ? (15 - w) : w;
#pragma unroll
    for (int kc = 0; kc < 2; ++kc)
      qf2[i][kc] = *(const bf16x8*)&smem[VQS_OFF + (mt * 16 + ln) * 64 +
                                         ((kc * 32 + qd * 8) ^ sx)];
  }
  __syncthreads();  // all q reads done; VQS writable

  // ---------------- Phase 2c: scatter v over VQS ([d][t], XOR-swizzled) ---
#pragma unroll
  for (int nt = 2; nt < 6; ++nt) {
    const int c0 = wn + nt * 16;
    if (c0 >= 128) {
#pragma unroll
      for (int mt = 0; mt < 4; ++mt) {
#pragma unroll
        for (int r = 0; r < 4; ++r) {
          const int t = wm + mt * 16 + qd * 4 + r;
          const int dv = c0 - 128 + ln;
          smem[VQS_OFF + dv * 256 + (t ^ ((dv & 7) << 3))] =
              f2b(acc[mt][nt][r]);
        }
      }
    }
  }
  __syncthreads();

  // ---------------- Phase 3: causal flash attention ----------------
  u16* Pw = smem + PLS_OFF + w * 640;
#pragma unroll
  for (int i = 0; i < 2; ++i) {
    const int mt = i ? (15 - w) : w;

    floatx4 oacc[4];
    float lsum[4];
#pragma unroll
    for (int dt = 0; dt < 4; ++dt) oacc[dt] = floatx4{0.f, 0.f, 0.f, 0.f};
#pragma unroll
    for (int r = 0; r < 4; ++r) lsum[r] = 0.f;

    const int cmax = mt >> 2;
    for (int c = 0; c < cmax; ++c)
      attn_chunk_f<false>(c, mt, lane, ln, qd, qf2[i], smem, Pw, oacc, lsum);
    attn_chunk_f<true>(cmax, mt, lane, ln, qd, qf2[i], smem, Pw, oacc, lsum);

#pragma unroll
    for (int off = 1; off < 16; off <<= 1)
#pragma unroll
      for (int r = 0; r < 4; ++r) lsum[r] += __shfl_xor(lsum[r], off);

    // y written with per-row col permutation for proj's swizzled read
#pragma unroll
    for (int r = 0; r < 4; ++r) {
      const float inv = 1.f / lsum[r];
      const int t = mt * 16 + qd * 4 + r;
      const int sy = (t & 7) << 3;
      u16* yo = y + ((size_t)b * T_DIM + t) * C_DIM + h * HS;
#pragma unroll
      for (int dt = 0; dt < 4; ++dt)
        yo[(dt * 16 + ln) ^ sy] = f2b(oacc[dt][r] * inv);
    }
  }
}

// ---------------------------------------------------------------------------
// Kernel C: output projection (r4-verified, unchanged).
// ---------------------------------------------------------------------------
__global__ __launch_bounds__(256) void proj_gemm(
    const u16* __restrict__ yb, const u16* __restrict__ Wpt,
    const float* __restrict__ bp, float* __restrict__ out) {
  __shared__ u16 As[128 * 64];
  __shared__ u16 Bs[128 * 64];
  const int row0 = blockIdx.x * 128;
  const int n0 = blockIdx.y * 128;
  const u16* a_rows = yb + (size_t)row0 * C_DIM;
  const u16* bt_rows = Wpt + (size_t)n0 * C_DIM;

  const int tid = threadIdx.x;
  const int lane = tid & 63;
  const int w = tid >> 6;
  const int lr = lane >> 3;
  const int lkc = (lane & 7) * 8;
  const int qd = lane >> 4;
  const int ln = lane & 15;
  const int sx = (ln & 7) << 3;
  const int mw = (w >> 1) * 64;
  const int nw = (w & 1) * 64;

  floatx4 acc[4][4];
#pragma unroll
  for (int i = 0; i < 4; ++i)
#pragma unroll
    for (int j = 0; j < 4; ++j) acc[i][j] = floatx4{0.f, 0.f, 0.f, 0.f};

  for (int kb = 0; kb < C_DIM / 64; ++kb) {
    const int k0 = kb * 64;
    __syncthreads();
#pragma unroll
    for (int s = 0; s < 4; ++s) {
      const int rbase = (s * 4 + w) * 8;
      gload_lds16(a_rows + (size_t)(rbase + lr) * C_DIM + k0 + lkc,
                  As + rbase * 64);
      gload_lds16(bt_rows + (size_t)(rbase + lr) * C_DIM + k0 + lkc,
                  Bs + rbase * 64);
    }
    __syncthreads();

#pragma unroll
    for (int kk = 0; kk < 2; ++kk) {
      bf16x8 af[4], bf[4];
#pragma unroll
      for (int mt = 0; mt < 4; ++mt)
        af[mt] = *(const bf16x8*)&As[(mw + mt * 16 + ln) * 64 +
                                     ((kk * 32 + qd * 8) ^ sx)];
#pragma unroll
      for (int nt = 0; nt < 4; ++nt)
        bf[nt] = *(const bf16x8*)&Bs[(nw + nt * 16 + ln) * 64 +
                                     ((kk * 32 + qd * 8) ^ sx)];
#pragma unroll
      for (int mt = 0; mt < 4; ++mt)
#pragma unroll
        for (int nt = 0; nt < 4; ++nt)
          acc[mt][nt] = __builtin_amdgcn_mfma_f32_16x16x32_bf16(
              af[mt], bf[nt], acc[mt][nt], 0, 0, 0);
    }
  }

#pragma unroll
  for (int nt = 0; nt < 4; ++nt) {
    const int col = n0 + nw + nt * 16 + ln;
    const float bias = bp[col];
#pragma unroll
    for (int mt = 0; mt < 4; ++mt) {
#pragma unroll
      for (int r = 0; r < 4; ++r) {
        const int grow = row0 + mw + mt * 16 + qd * 4 + r;
        out[(size_t)grow * C_DIM + col] = acc[mt][nt][r] + bias;
      }
    }
  }
}

// ---------------------------------------------------------------------------
extern "C" void kernel_launch(void* const* d_in, const int* in_sizes, int n_in,
                              void* d_out, int out_size, void* d_ws, size_t ws_size,
                              hipStream_t stream) {
  const float* x  = (const float*)d_in[0];
  const float* Wq = (const float*)d_in[1];
  const float* Wk = (const float*)d_in[2];
  const float* Wv = (const float*)d_in[3];
  const float* Wp = (const float*)d_in[4];
  const float* bp = (const float*)d_in[5];
  float* out = (float*)d_out;

  const size_t n_x = (size_t)NROWS * C_DIM;  // 12,582,912

  u16* Wh  = (u16*)d_ws;                       // [6][192][384] (K-permuted)
  u16* Wpt = Wh + (size_t)H_NUM * 192 * C_DIM; // [384][384]   (K-permuted)
  u16* xb  = Wpt + C_DIM * C_DIM;              // [32768][384] (K-permuted)
  u16* y   = xb + n_x;                         // [32768][384] (col-permuted)
  // ws: ~0.9 + 0.3 + 24 + 24 = ~49 MB

  prep_kernel<<<6144 + 2304, 256, 0, stream>>>(x, Wq, Wk, Wv, Wp, xb, Wh, Wpt);
  qkv_attn_fused<<<dim3(B_DIM, H_NUM), 512, 0, stream>>>(xb, Wh, y);
  proj_gemm<<<dim3(NROWS / 128, 3), 256, 0, stream>>>(y, Wpt, bp, out);
}

// Round 7
// 182.058 us; speedup vs baseline: 1.6133x; 1.0263x over previous
//
#include <hip/hip_runtime.h>
#include <hip/hip_bf16.h>

#define C_DIM 384
#define H_NUM 6
#define HS    64
#define B_DIM 128
#define T_DIM 256
#define NROWS (B_DIM * T_DIM)  // 32768

typedef unsigned short u16;
typedef unsigned int u32;
typedef short bf16x8 __attribute__((ext_vector_type(8)));
typedef float floatx4 __attribute__((ext_vector_type(4)));

__device__ __forceinline__ u16 f2b(float f) {
  __hip_bfloat16 h = __float2bfloat16(f);
  u16 u;
  __builtin_memcpy(&u, &h, 2);
  return u;
}
// async global->LDS, 16B per lane. LDS dest is wave-uniform base + lane*16.
__device__ __forceinline__ void gload_lds16(const void* g, void* lds) {
  __builtin_amdgcn_global_load_lds(
      (const __attribute__((address_space(1))) u32*)g,
      (__attribute__((address_space(3))) u32*)lds, 16, 0, 0);
}

// ---------------------------------------------------------------------------
// Prep (r4-verified, unchanged): x fp32 -> bf16 xb (K-permuted per row) AND
// weights -> bf16 (K-permuted). Rule-21: linear DMA dest + inverse-permuted
// source + XOR'd fragment read in the consumer.
// ---------------------------------------------------------------------------
__global__ __launch_bounds__(256) void prep_kernel(
    const float* __restrict__ x, const float* __restrict__ Wq,
    const float* __restrict__ Wk, const float* __restrict__ Wv,
    const float* __restrict__ Wp, u16* __restrict__ xb,
    u16* __restrict__ Wh, u16* __restrict__ Wpt) {
  const int bid = blockIdx.x;
  const int tid = threadIdx.x;
  if (bid < 6144) {  // x: 12,582,912 elems = 6144*256 threads x 8
    const int i = bid * 256 + tid;
    const int row = (i * 8) / C_DIM;
    const int c8 = (i * 8) % C_DIM;
    const int cs = c8 ^ ((row & 7) << 3);  // XOR bits 3-5, within 64-block
    const float* p = x + (size_t)row * C_DIM + cs;
    const float4 f0 = *(const float4*)p;
    const float4 f1 = *(const float4*)(p + 4);
    bf16x8 pk;
    pk[0] = (short)f2b(f0.x); pk[1] = (short)f2b(f0.y);
    pk[2] = (short)f2b(f0.z); pk[3] = (short)f2b(f0.w);
    pk[4] = (short)f2b(f1.x); pk[5] = (short)f2b(f1.y);
    pk[6] = (short)f2b(f1.z); pk[7] = (short)f2b(f1.w);
    ((bf16x8*)xb)[i] = pk;
  } else {  // weights: 442368 + 147456 = 589824 = 2304*256
    const int idx = (bid - 6144) * 256 + tid;
    const int WHN = H_NUM * 192 * C_DIM;  // 442368
    if (idx < WHN) {
      int h = idx / (192 * C_DIM);
      int rem = idx % (192 * C_DIM);
      int r = rem / C_DIM, c = rem % C_DIM;
      int tz = r >> 6, d = r & 63;
      const int cs = c ^ ((r & 7) << 3);
      const float* W = (tz == 0) ? Wq : (tz == 1) ? Wk : Wv;
      Wh[idx] = f2b(W[((size_t)h * C_DIM + cs) * HS + d]);
    } else {
      int j = idx - WHN;
      int n = j / C_DIM, c = j % C_DIM;
      const int cs = c ^ ((n & 7) << 3);
      Wpt[j] = f2b(Wp[cs * C_DIM + n]);
    }
  }
}

// ---------------------------------------------------------------------------
// FUSED kernel (r4-verified, reverted exactly): per-(b,h) block, 8 waves.
// Phase 1: GEMM 256x192x384, DMA staging, DOUBLE-BUFFERED, counted vmcnt(7).
// Phase 2: epilogue scatter q/k/v to LDS. Phase 3: causal flash attention.
// LDS (u16): GEMM AS0=0 AS1=16384 BS0=32768 BS1=45056; attn QS=0 KLS=16384
// VTS=32768 PLS=49152. Total 58368 u16 = 116736 B.
// ---------------------------------------------------------------------------
#define AS0_OFF 0
#define AS1_OFF 16384
#define BS0_OFF 32768
#define BS1_OFF 45056
#define QS_OFF  0
#define KLS_OFF 16384
#define VTS_OFF 32768
#define PLS_OFF 49152

template <bool DIAG>
__device__ __forceinline__ void attn_chunk_f(int c, int mt, int lane, int ln,
                                             int qd, const bf16x8* qf,
                                             const u16* smem, u16* Pw,
                                             floatx4* oacc, float* lsum) {
  floatx4 sacc[4];
#pragma unroll
  for (int st = 0; st < 4; ++st) {
    sacc[st] = floatx4{0.f, 0.f, 0.f, 0.f};
#pragma unroll
    for (int kc = 0; kc < 2; ++kc) {
      bf16x8 kf = *(const bf16x8*)&smem[KLS_OFF + ((c * 4 + st) * 2 + kc) * 512 +
                                        lane * 8];
      sacc[st] =
          __builtin_amdgcn_mfma_f32_16x16x32_bf16(qf[kc], kf, sacc[st], 0, 0, 0);
    }
  }
#pragma unroll
  for (int st = 0; st < 4; ++st) {
#pragma unroll
    for (int r = 0; r < 4; ++r) {
      const float sv = sacc[st][r] * 0.125f;
      float p = __expf(sv);
      if (DIAG) {
        const bool ok = (c * 64 + st * 16 + ln) <= (mt * 16 + qd * 4 + r);
        p = ok ? p : 0.f;
      }
      lsum[r] += p;
      Pw[(qd * 4 + r) * 72 + st * 16 + ln] = f2b(p);
    }
  }
#pragma unroll
  for (int kc2 = 0; kc2 < 2; ++kc2) {
    bf16x8 pf = *(const bf16x8*)&Pw[ln * 72 + kc2 * 32 + qd * 8];
#pragma unroll
    for (int dt = 0; dt < 4; ++dt) {
      bf16x8 vf = *(const bf16x8*)&smem[VTS_OFF + (dt * 16 + ln) * 256 +
                                        ((c * 64 + kc2 * 32 + qd * 8) ^
                                         ((ln & 7) << 3))];
      oacc[dt] =
          __builtin_amdgcn_mfma_f32_16x16x32_bf16(pf, vf, oacc[dt], 0, 0, 0);
    }
  }
}

__global__ __launch_bounds__(512) void qkv_attn_fused(
    const u16* __restrict__ xb, const u16* __restrict__ Wh,
    u16* __restrict__ y) {
  __shared__ __align__(16) u16 smem[58368];  // 116736 B
  const int b = blockIdx.x;
  const int h = blockIdx.y;
  const u16* a_rows = xb + (size_t)b * 256 * C_DIM;
  const u16* wbase = Wh + (size_t)h * 192 * C_DIM;

  const int tid = threadIdx.x;
  const int lane = tid & 63;
  const int w = tid >> 6;          // 0..7
  const int lr = lane >> 3;        // DMA staging row within 8-row strip
  const int lkc = (lane & 7) * 8;  // DMA staging col (u16)
  const int qd = lane >> 4;
  const int ln = lane & 15;
  const int sx = (ln & 7) << 3;    // fragment-read XOR key
  const int wm = (w >> 1) * 64;    // GEMM row group (0,64,128,192)
  const int wn = (w & 1) * 96;     // GEMM col group (0,96)

  // ---------------- Phase 1: GEMM (dbuf, counted vmcnt) ----------------
  floatx4 acc[4][6];
#pragma unroll
  for (int i = 0; i < 4; ++i)
#pragma unroll
    for (int j = 0; j < 6; ++j) acc[i][j] = floatx4{0.f, 0.f, 0.f, 0.f};

  // prologue: stage kb=0 into buf0 (7 DMA issues/thread)
#pragma unroll
  for (int s = 0; s < 4; ++s) {
    const int rbase = (s * 8 + w) * 8;
    gload_lds16(a_rows + (size_t)(rbase + lr) * C_DIM + lkc,
                smem + AS0_OFF + rbase * 64);
  }
#pragma unroll
  for (int s = 0; s < 3; ++s) {
    const int rbase = (s * 8 + w) * 8;
    gload_lds16(wbase + (size_t)(rbase + lr) * C_DIM + lkc,
                smem + BS0_OFF + rbase * 64);
  }

  for (int kb = 0; kb < 6; ++kb) {
    const int pa = (kb & 1) ? AS1_OFF : AS0_OFF;
    const int pb = (kb & 1) ? BS1_OFF : BS0_OFF;
    if (kb < 5) {
      // issue next tile into the other buffers (reads of them ended at the
      // trailing barrier of iter kb-1)
      const int qa = (kb & 1) ? AS0_OFF : AS1_OFF;
      const int qb = (kb & 1) ? BS0_OFF : BS1_OFF;
      const int k0 = (kb + 1) * 64;
#pragma unroll
      for (int s = 0; s < 4; ++s) {
        const int rbase = (s * 8 + w) * 8;
        gload_lds16(a_rows + (size_t)(rbase + lr) * C_DIM + k0 + lkc,
                    smem + qa + rbase * 64);
      }
#pragma unroll
      for (int s = 0; s < 3; ++s) {
        const int rbase = (s * 8 + w) * 8;
        gload_lds16(wbase + (size_t)(rbase + lr) * C_DIM + k0 + lkc,
                    smem + qb + rbase * 64);
      }
      // 14 outstanding; wait the oldest 7 (current tile), keep 7 in flight
      asm volatile("s_waitcnt vmcnt(7)" ::: "memory");
    } else {
      asm volatile("s_waitcnt vmcnt(0)" ::: "memory");
    }
    __builtin_amdgcn_s_barrier();
    __builtin_amdgcn_sched_barrier(0);

#pragma unroll
    for (int kk = 0; kk < 2; ++kk) {
      bf16x8 af[4], bf[6];
#pragma unroll
      for (int mt = 0; mt < 4; ++mt)
        af[mt] = *(const bf16x8*)&smem[pa + (wm + mt * 16 + ln) * 64 +
                                       ((kk * 32 + qd * 8) ^ sx)];
#pragma unroll
      for (int nt = 0; nt < 6; ++nt)
        bf[nt] = *(const bf16x8*)&smem[pb + (wn + nt * 16 + ln) * 64 +
                                       ((kk * 32 + qd * 8) ^ sx)];
#pragma unroll
      for (int mt = 0; mt < 4; ++mt)
#pragma unroll
        for (int nt = 0; nt < 6; ++nt)
          acc[mt][nt] = __builtin_amdgcn_mfma_f32_16x16x32_bf16(
              af[mt], bf[nt], acc[mt][nt], 0, 0, 0);
    }
    __builtin_amdgcn_sched_barrier(0);
    __builtin_amdgcn_s_barrier();  // reads of pa/pb done; next iter may write
  }

  // ---------------- Phase 2: epilogue scatter to LDS ----------------
  // C/D layout: col = c0 + ln, row t = wm + mt*16 + qd*4 + r.
#pragma unroll
  for (int nt = 0; nt < 6; ++nt) {
    const int c0 = wn + nt * 16;  // wave-uniform
#pragma unroll
    for (int mt = 0; mt < 4; ++mt) {
#pragma unroll
      for (int r = 0; r < 4; ++r) {
        const int t = wm + mt * 16 + qd * 4 + r;
        const u16 val = f2b(acc[mt][nt][r]);
        if (c0 < 64) {  // q -> linear [t][d]
          smem[QS_OFF + t * 64 + c0 + ln] = val;
        } else if (c0 < 128) {  // k -> fragment-major Kls
          const int d = c0 - 64 + ln;
          smem[KLS_OFF + ((t >> 4) << 10) + ((d >> 5) << 9) +
               (((d >> 3) & 3) << 7) + ((t & 15) << 3) + (d & 7)] = val;
        } else {  // v -> vTS [d][t], XOR-swizzled col
          const int dv = c0 - 128 + ln;
          smem[VTS_OFF + dv * 256 + (t ^ ((dv & 7) << 3))] = val;
        }
      }
    }
  }
  __syncthreads();

  // ---------------- Phase 3: causal flash attention ----------------
  u16* Pw = smem + PLS_OFF + w * 1152;
#pragma unroll
  for (int i = 0; i < 2; ++i) {
    const int mt = i ? (15 - w) : w;
    bf16x8 qf[2];
#pragma unroll
    for (int kc = 0; kc < 2; ++kc)
      qf[kc] = *(const bf16x8*)&smem[QS_OFF + (mt * 16 + ln) * 64 + kc * 32 +
                                     qd * 8];

    floatx4 oacc[4];
    float lsum[4];
#pragma unroll
    for (int dt = 0; dt < 4; ++dt) oacc[dt] = floatx4{0.f, 0.f, 0.f, 0.f};
#pragma unroll
    for (int r = 0; r < 4; ++r) lsum[r] = 0.f;

    const int cmax = mt >> 2;
    for (int c = 0; c < cmax; ++c)
      attn_chunk_f<false>(c, mt, lane, ln, qd, qf, smem, Pw, oacc, lsum);
    attn_chunk_f<true>(cmax, mt, lane, ln, qd, qf, smem, Pw, oacc, lsum);

#pragma unroll
    for (int off = 1; off < 16; off <<= 1)
#pragma unroll
      for (int r = 0; r < 4; ++r) lsum[r] += __shfl_xor(lsum[r], off);

    // y written with per-row col permutation for proj's swizzled read
#pragma unroll
    for (int r = 0; r < 4; ++r) {
      const float inv = 1.f / lsum[r];
      const int t = mt * 16 + qd * 4 + r;
      const int sy = (t & 7) << 3;
      u16* yo = y + ((size_t)b * T_DIM + t) * C_DIM + h * HS;
#pragma unroll
      for (int dt = 0; dt < 4; ++dt)
        yo[(dt * 16 + ln) ^ sy] = f2b(oacc[dt][r] * inv);
    }
  }
}

// ---------------------------------------------------------------------------
// Kernel C: output projection. NEW: dbuf + counted vmcnt(8), transplanted
// from the r4-verified fused GEMM loop (same barrier/race structure).
// LDS 64 KB: AS0@0, AS1@8192, BS0@16384, BS1@24576 (u16 offsets).
// ---------------------------------------------------------------------------
#define PAS0 0
#define PAS1 8192
#define PBS0 16384
#define PBS1 24576

__global__ __launch_bounds__(256) void proj_gemm(
    const u16* __restrict__ yb, const u16* __restrict__ Wpt,
    const float* __restrict__ bp, float* __restrict__ out) {
  __shared__ __align__(16) u16 smem[32768];  // 65536 B
  const int row0 = blockIdx.x * 128;
  const int n0 = blockIdx.y * 128;
  const u16* a_rows = yb + (size_t)row0 * C_DIM;
  const u16* bt_rows = Wpt + (size_t)n0 * C_DIM;

  const int tid = threadIdx.x;
  const int lane = tid & 63;
  const int w = tid >> 6;
  const int lr = lane >> 3;
  const int lkc = (lane & 7) * 8;
  const int qd = lane >> 4;
  const int ln = lane & 15;
  const int sx = (ln & 7) << 3;
  const int mw = (w >> 1) * 64;
  const int nw = (w & 1) * 64;

  floatx4 acc[4][4];
#pragma unroll
  for (int i = 0; i < 4; ++i)
#pragma unroll
    for (int j = 0; j < 4; ++j) acc[i][j] = floatx4{0.f, 0.f, 0.f, 0.f};

  // prologue: stage kb=0 into buf0 (8 DMA issues/thread)
#pragma unroll
  for (int s = 0; s < 4; ++s) {
    const int rbase = (s * 4 + w) * 8;
    gload_lds16(a_rows + (size_t)(rbase + lr) * C_DIM + lkc,
                smem + PAS0 + rbase * 64);
    gload_lds16(bt_rows + (size_t)(rbase + lr) * C_DIM + lkc,
                smem + PBS0 + rbase * 64);
  }

  for (int kb = 0; kb < 6; ++kb) {
    const int pa = (kb & 1) ? PAS1 : PAS0;
    const int pb = (kb & 1) ? PBS1 : PBS0;
    if (kb < 5) {
      const int qa = (kb & 1) ? PAS0 : PAS1;
      const int qb = (kb & 1) ? PBS0 : PBS1;
      const int k0 = (kb + 1) * 64;
#pragma unroll
      for (int s = 0; s < 4; ++s) {
        const int rbase = (s * 4 + w) * 8;
        gload_lds16(a_rows + (size_t)(rbase + lr) * C_DIM + k0 + lkc,
                    smem + qa + rbase * 64);
        gload_lds16(bt_rows + (size_t)(rbase + lr) * C_DIM + k0 + lkc,
                    smem + qb + rbase * 64);
      }
      // 16 outstanding; wait the oldest 8 (current tile), keep 8 in flight
      asm volatile("s_waitcnt vmcnt(8)" ::: "memory");
    } else {
      asm volatile("s_waitcnt vmcnt(0)" ::: "memory");
    }
    __builtin_amdgcn_s_barrier();
    __builtin_amdgcn_sched_barrier(0);

#pragma unroll
    for (int kk = 0; kk < 2; ++kk) {
      bf16x8 af[4], bf[4];
#pragma unroll
      for (int mt = 0; mt < 4; ++mt)
        af[mt] = *(const bf16x8*)&smem[pa + (mw + mt * 16 + ln) * 64 +
                                       ((kk * 32 + qd * 8) ^ sx)];
#pragma unroll
      for (int nt = 0; nt < 4; ++nt)
        bf[nt] = *(const bf16x8*)&smem[pb + (nw + nt * 16 + ln) * 64 +
                                       ((kk * 32 + qd * 8) ^ sx)];
#pragma unroll
      for (int mt = 0; mt < 4; ++mt)
#pragma unroll
        for (int nt = 0; nt < 4; ++nt)
          acc[mt][nt] = __builtin_amdgcn_mfma_f32_16x16x32_bf16(
              af[mt], bf[nt], acc[mt][nt], 0, 0, 0);
    }
    __builtin_amdgcn_sched_barrier(0);
    __builtin_amdgcn_s_barrier();  // reads of pa/pb done; next iter may write
  }

#pragma unroll
  for (int nt = 0; nt < 4; ++nt) {
    const int col = n0 + nw + nt * 16 + ln;
    const float bias = bp[col];
#pragma unroll
    for (int mt = 0; mt < 4; ++mt) {
#pragma unroll
      for (int r = 0; r < 4; ++r) {
        const int grow = row0 + mw + mt * 16 + qd * 4 + r;
        out[(size_t)grow * C_DIM + col] = acc[mt][nt][r] + bias;
      }
    }
  }
}

// ---------------------------------------------------------------------------
extern "C" void kernel_launch(void* const* d_in, const int* in_sizes, int n_in,
                              void* d_out, int out_size, void* d_ws, size_t ws_size,
                              hipStream_t stream) {
  const float* x  = (const float*)d_in[0];
  const float* Wq = (const float*)d_in[1];
  const float* Wk = (const float*)d_in[2];
  const float* Wv = (const float*)d_in[3];
  const float* Wp = (const float*)d_in[4];
  const float* bp = (const float*)d_in[5];
  float* out = (float*)d_out;

  const size_t n_x = (size_t)NROWS * C_DIM;  // 12,582,912

  u16* Wh  = (u16*)d_ws;                       // [6][192][384] (K-permuted)
  u16* Wpt = Wh + (size_t)H_NUM * 192 * C_DIM; // [384][384]   (K-permuted)
  u16* xb  = Wpt + C_DIM * C_DIM;              // [32768][384] (K-permuted)
  u16* y   = xb + n_x;                         // [32768][384] (col-permuted)
  // ws: ~0.9 + 0.3 + 24 + 24 = ~49 MB

  prep_kernel<<<6144 + 2304, 256, 0, stream>>>(x, Wq, Wk, Wv, Wp, xb, Wh, Wpt);
  qkv_attn_fused<<<dim3(B_DIM, H_NUM), 512, 0, stream>>>(xb, Wh, y);
  proj_gemm<<<dim3(NROWS / 128, 3), 256, 0, stream>>>(y, Wpt, bp, out);
}